// Round 2
// baseline (207.736 us; speedup 1.0000x reference)
//
#include <hip/hip_runtime.h>
#include <hip/hip_bf16.h>
#include <stdint.h>

typedef __attribute__((ext_vector_type(4))) float f32x4;
typedef __attribute__((ext_vector_type(8))) short bf16x8;

constexpr int SDIM = 2048;
constexpr int KDIM = 4096;   // INT (3840) + FP (256), contiguous
constexpr int ODIM = 4096;
constexpr int INTD = 3840;
constexpr int FPD  = 256;

// RNE float->bf16 (bit-exact with __float2bfloat16 for finite values)
__device__ __forceinline__ unsigned short f2bf(float f) {
  union { float f; unsigned u; } a; a.f = f;
  unsigned r = a.u + 0x7fffu + ((a.u >> 16) & 1u);
  return (unsigned short)(r >> 16);
}

__device__ __forceinline__ void gload16(const void* g, void* l) {
  __builtin_amdgcn_global_load_lds(
      (const __attribute__((address_space(1))) void*)g,
      (__attribute__((address_space(3))) void*)l, 16, 0, 0);
}

// ---------------------------------------------------------------------------
// Kernel 1: per-row gather, absmax, quantize INT region; scale+gather FP region
// A[s,k] bf16: k<3840 -> round(int_x/qscale) (integers, exact in bf16)
//             k>=3840 -> fp_x / qscale
// ---------------------------------------------------------------------------
__global__ __launch_bounds__(256) void prep_x_kernel(
    const float* __restrict__ x,
    const int* __restrict__ int_idx,     // harness delivers integer inputs as int32
    const int* __restrict__ fp_idx,
    unsigned short* __restrict__ A,
    float* __restrict__ qs)
{
  __shared__ float row[4096];
  __shared__ float red[4];
  const int s = blockIdx.x;
  const int t = threadIdx.x;
  const float* xr = x + (size_t)s * 4096;
  #pragma unroll
  for (int i = 0; i < 4; ++i)
    ((float4*)row)[t + 256 * i] = ((const float4*)xr)[t + 256 * i];
  __syncthreads();

  float vals[15];
  float m = 0.f;
  #pragma unroll
  for (int i = 0; i < 15; ++i) {
    int j = t + (i << 8);                 // coalesced over the 3840 int slots
    float v = row[int_idx[j]];
    vals[i] = v;
    m = fmaxf(m, fabsf(v));
  }
  #pragma unroll
  for (int off = 32; off; off >>= 1)
    m = fmaxf(m, __shfl_xor(m, off));
  if ((t & 63) == 0) red[t >> 6] = m;
  __syncthreads();
  const float mx = fmaxf(fmaxf(red[0], red[1]), fmaxf(red[2], red[3]));
  const float qscale = mx / 127.0f;       // exactly as reference: max/QMAX
  if (t == 0) qs[s] = qscale;

  unsigned short* Ar = A + (size_t)s * KDIM;
  #pragma unroll
  for (int i = 0; i < 15; ++i) {
    int j = t + (i << 8);
    float q = rintf(vals[i] / qscale);    // rintf == round-half-even == jnp.round
    q = fminf(fmaxf(q, -128.f), 127.f);
    Ar[j] = f2bf(q);
  }
  const float fv = row[fp_idx[t]];
  Ar[INTD + t] = f2bf(fv / qscale);       // pre-scale FP region by 1/qscale
}

// ---------------------------------------------------------------------------
// Kernel 2: weights -> bf16.  INT region cast (integers, exact).
// FP region pre-scaled by 1/weights_scales[o].
// ---------------------------------------------------------------------------
__global__ __launch_bounds__(256) void prep_w_kernel(
    const float* __restrict__ iw,
    const float* __restrict__ fw,
    const float* __restrict__ wsc,
    unsigned short* __restrict__ W)
{
  const int o = blockIdx.x;
  const int t = threadIdx.x;
  const float* iwr = iw + (size_t)o * INTD;
  unsigned short* Wr = W + (size_t)o * KDIM;
  for (int g = t; g < 960; g += 256) {    // 3840 floats = 960 float4
    float4 v = ((const float4*)iwr)[g];
    ushort4 u = { f2bf(v.x), f2bf(v.y), f2bf(v.z), f2bf(v.w) };
    ((ushort4*)Wr)[g] = u;
  }
  const float w = wsc[o];
  Wr[INTD + t] = f2bf(fw[(size_t)o * FPD + t] / w);
}

// ---------------------------------------------------------------------------
// Kernel 3: bf16 GEMM, out[s,o] = (A row s . W row o) * wsc[o]*qs[s] + bias[o]
// m97 structure: 128x128 tile, BK=64, 4 waves (2x2), double-buffered LDS,
// global_load_lds width=16, XOR chunk swizzle (source-side + read-side).
// ---------------------------------------------------------------------------
__global__ __launch_bounds__(256, 2) void gemm_kernel(
    const unsigned short* __restrict__ A,   // SDIM x KDIM
    const unsigned short* __restrict__ W,   // ODIM x KDIM
    const float* __restrict__ qs,
    const float* __restrict__ wsc,
    const float* __restrict__ bias,
    float* __restrict__ out)                // SDIM x ODIM
{
  __shared__ unsigned short lds[2][2][128][64];   // 64 KiB total
  const int tid  = threadIdx.x;
  const int lane = tid & 63;
  const int wid  = tid >> 6;
  const int wr   = wid >> 1, wc = wid & 1;

  // XCD-aware swizzle: 512 blocks, 512 % 8 == 0 -> simple bijective remap
  const int bid = blockIdx.x;
  const int swz = (bid & 7) * 64 + (bid >> 3);
  const int bm  = swz & 15;     // 16 blocks along S
  const int bn  = swz >> 4;     // 32 blocks along OUT
  const int srow0 = bm * 128;
  const int ocol0 = bn * 128;

  // Precompute swizzled byte offsets within a [128][64] bf16 tile.
  // Logical element (row, k): chunk lc = k/8; physical chunk = lc ^ (row & 7).
  int aoff[2][4], boff[2][4];
  #pragma unroll
  for (int kk = 0; kk < 2; ++kk) {
    #pragma unroll
    for (int i = 0; i < 4; ++i) {
      const int rowA = wr * 64 + i * 16 + (lane & 15);
      const int rowB = wc * 64 + i * 16 + (lane & 15);
      const int lc   = kk * 4 + (lane >> 4);
      aoff[kk][i] = rowA * 128 + ((lc ^ (rowA & 7)) * 16);
      boff[kk][i] = rowB * 128 + ((lc ^ (rowB & 7)) * 16);
    }
  }

  auto stage = [&](int kt, int buf) {
    const char* Ag = (const char*)(A + (size_t)srow0 * KDIM + kt);
    const char* Wg = (const char*)(W + (size_t)ocol0 * KDIM + kt);
    char* Al = (char*)&lds[buf][0][0][0];
    char* Bl = (char*)&lds[buf][1][0][0];
    #pragma unroll
    for (int q = 0; q < 4; ++q) {
      // lane l lands at LDS slot (row = base+l/8, phys chunk = l&7); fetch the
      // global data of logical chunk (l&7)^(row&7) so read-side XOR un-swizzles.
      const int rloc = wid * 32 + q * 8 + (lane >> 3);
      const int cl   = (lane & 7) ^ (rloc & 7);
      gload16(Ag + (size_t)rloc * (KDIM * 2) + cl * 16,
              Al + (wid * 32 + q * 8) * 128);
      gload16(Wg + (size_t)rloc * (KDIM * 2) + cl * 16,
              Bl + (wid * 32 + q * 8) * 128);
    }
  };

  f32x4 acc[4][4];
  #pragma unroll
  for (int i = 0; i < 4; ++i)
    #pragma unroll
    for (int j = 0; j < 4; ++j)
      acc[i][j] = f32x4{0.f, 0.f, 0.f, 0.f};

  stage(0, 0);
  int cur = 0;
  constexpr int NT = KDIM / 64;
  for (int t = 0; t < NT; ++t) {
    __syncthreads();                       // drains vmcnt: lds[cur] is ready
    if (t + 1 < NT) stage((t + 1) * 64, cur ^ 1);   // overlaps compute below
    const char* Al = (const char*)&lds[cur][0][0][0];
    const char* Bl = (const char*)&lds[cur][1][0][0];
    #pragma unroll
    for (int kk = 0; kk < 2; ++kk) {
      bf16x8 af[4], bv[4];
      #pragma unroll
      for (int i = 0; i < 4; ++i) af[i] = *(const bf16x8*)(Al + aoff[kk][i]);
      #pragma unroll
      for (int j = 0; j < 4; ++j) bv[j] = *(const bf16x8*)(Bl + boff[kk][j]);
      #pragma unroll
      for (int i = 0; i < 4; ++i)
        #pragma unroll
        for (int j = 0; j < 4; ++j)
          acc[i][j] = __builtin_amdgcn_mfma_f32_16x16x32_bf16(
              af[i], bv[j], acc[i][j], 0, 0, 0);
    }
    cur ^= 1;
  }

  // Epilogue: C/D layout col = lane&15 (n), row = (lane>>4)*4 + reg (m)
  const int r4 = (lane >> 4) * 4;
  const int cn = lane & 15;
  #pragma unroll
  for (int j = 0; j < 4; ++j) {
    const int o  = ocol0 + wc * 64 + j * 16 + cn;
    const float wo = wsc[o];
    const float bo = bias[o];
    #pragma unroll
    for (int i = 0; i < 4; ++i) {
      const int sbase = srow0 + wr * 64 + i * 16 + r4;
      #pragma unroll
      for (int r = 0; r < 4; ++r) {
        const int srow = sbase + r;
        out[(size_t)srow * ODIM + o] = acc[i][j][r] * wo * qs[srow] + bo;
      }
    }
  }
}

// ---------------------------------------------------------------------------
extern "C" void kernel_launch(void* const* d_in, const int* in_sizes, int n_in,
                              void* d_out, int out_size, void* d_ws, size_t ws_size,
                              hipStream_t stream) {
  const float* x    = (const float*)d_in[0];
  const float* iw   = (const float*)d_in[1];
  const float* fw   = (const float*)d_in[2];
  const float* wsc  = (const float*)d_in[3];
  const float* bias = (const float*)d_in[4];
  const int* int_idx = (const int*)d_in[5];   // harness: integer inputs are int32
  const int* fp_idx  = (const int*)d_in[6];
  float* out = (float*)d_out;

  unsigned short* A = (unsigned short*)d_ws;           // 2048*4096*2 = 16 MiB
  unsigned short* W = A + (size_t)SDIM * KDIM;         // 4096*4096*2 = 32 MiB
  float* qs = (float*)(W + (size_t)ODIM * KDIM);       // 8 KiB

  prep_x_kernel<<<SDIM, 256, 0, stream>>>(x, int_idx, fp_idx, A, qs);
  prep_w_kernel<<<ODIM, 256, 0, stream>>>(iw, fw, wsc, W);
  gemm_kernel<<<512, 256, 0, stream>>>(A, W, qs, wsc, bias, out);
}

// Round 3
// 183.616 us; speedup vs baseline: 1.1314x; 1.1314x over previous
//
#include <hip/hip_runtime.h>
#include <hip/hip_bf16.h>
#include <stdint.h>

typedef __attribute__((ext_vector_type(4))) float f32x4;
typedef __attribute__((ext_vector_type(8))) short bf16x8;
typedef __attribute__((ext_vector_type(4))) int i32x4;

constexpr int SDIM = 2048;
constexpr int ODIM = 4096;
constexpr int INTD = 3840;
constexpr int FPD  = 256;

// RNE float->bf16
__device__ __forceinline__ unsigned short f2bf(float f) {
  union { float f; unsigned u; } a; a.f = f;
  unsigned r = a.u + 0x7fffu + ((a.u >> 16) & 1u);
  return (unsigned short)(r >> 16);
}

__device__ __forceinline__ void gload16(const void* g, void* l) {
  __builtin_amdgcn_global_load_lds(
      (const __attribute__((address_space(1))) void*)g,
      (__attribute__((address_space(3))) void*)l, 16, 0, 0);
}

// ---------------------------------------------------------------------------
// Kernel 1: gather + absmax + quantize INT region -> i8; gather FP region -> bf16
// ---------------------------------------------------------------------------
__global__ __launch_bounds__(256) void prep_x_kernel(
    const float* __restrict__ x,
    const int* __restrict__ int_idx,
    const int* __restrict__ fp_idx,
    unsigned* __restrict__ A8,          // [SDIM][INTD/4] packed i8x4
    unsigned short* __restrict__ Afp,   // [SDIM][FPD] bf16
    float* __restrict__ qs)
{
  __shared__ float row[4096];
  __shared__ float red[4];
  const int s = blockIdx.x;
  const int t = threadIdx.x;
  const float* xr = x + (size_t)s * 4096;
  #pragma unroll
  for (int i = 0; i < 4; ++i)
    ((float4*)row)[t + 256 * i] = ((const float4*)xr)[t + 256 * i];
  __syncthreads();

  // 3840 ints = 960 groups of 4; thread t owns groups t, t+256, t+512, t+768(<960)
  float vals[16];
  float m = 0.f;
  #pragma unroll
  for (int i = 0; i < 4; ++i) {
    const int g = t + (i << 8);
    if (g < 960) {
      int4 idx = ((const int4*)int_idx)[g];
      float v0 = row[idx.x], v1 = row[idx.y], v2 = row[idx.z], v3 = row[idx.w];
      vals[i*4+0] = v0; vals[i*4+1] = v1; vals[i*4+2] = v2; vals[i*4+3] = v3;
      m = fmaxf(m, fmaxf(fmaxf(fabsf(v0), fabsf(v1)), fmaxf(fabsf(v2), fabsf(v3))));
    }
  }
  #pragma unroll
  for (int off = 32; off; off >>= 1)
    m = fmaxf(m, __shfl_xor(m, off));
  if ((t & 63) == 0) red[t >> 6] = m;
  __syncthreads();
  const float mx = fmaxf(fmaxf(red[0], red[1]), fmaxf(red[2], red[3]));
  const float qscale = mx / 127.0f;       // exactly as reference
  if (t == 0) qs[s] = qscale;

  unsigned* Ar = A8 + (size_t)s * 960;
  #pragma unroll
  for (int i = 0; i < 4; ++i) {
    const int g = t + (i << 8);
    if (g < 960) {
      unsigned pk = 0;
      #pragma unroll
      for (int e = 0; e < 4; ++e) {
        float q = rintf(vals[i*4+e] / qscale);   // round-half-even == jnp.round
        q = fminf(fmaxf(q, -128.f), 127.f);
        pk |= ((unsigned)((int)q & 255)) << (e * 8);
      }
      Ar[g] = pk;
    }
  }
  Afp[(size_t)s * FPD + t] = f2bf(row[fp_idx[t]]);   // raw fp_x (unscaled)
}

// ---------------------------------------------------------------------------
// Kernel 2: int weights -> i8 (exact); fp weights -> bf16 (raw, unscaled)
// ---------------------------------------------------------------------------
__global__ __launch_bounds__(256) void prep_w_kernel(
    const float* __restrict__ iw,
    const float* __restrict__ fw,
    unsigned* __restrict__ W8,          // [ODIM][INTD/4] packed i8x4
    unsigned short* __restrict__ Wfp)   // [ODIM][FPD] bf16
{
  const int o = blockIdx.x;
  const int t = threadIdx.x;
  const float* iwr = iw + (size_t)o * INTD;
  unsigned* Wr = W8 + (size_t)o * 960;
  for (int g = t; g < 960; g += 256) {
    float4 v = ((const float4*)iwr)[g];
    int q0 = __float2int_rn(v.x), q1 = __float2int_rn(v.y);
    int q2 = __float2int_rn(v.z), q3 = __float2int_rn(v.w);
    Wr[g] = (unsigned)(q0 & 255) | ((unsigned)(q1 & 255) << 8) |
            ((unsigned)(q2 & 255) << 16) | ((unsigned)(q3 & 255) << 24);
  }
  Wfp[(size_t)o * FPD + t] = f2bf(fw[(size_t)o * FPD + t]);
}

// ---------------------------------------------------------------------------
// Kernel 3: fused i8 GEMM (K=3840) + bf16 GEMM (K=256)
// out[s,o] = (i8dot)*wsc[o]*qs[s] + (fp dot) + bias[o]
// 128x128 tile, 4 waves, double-buffered [128 rows][128 B] LDS tiles,
// global_load_lds w=16, XOR chunk swizzle (source-side + read-side).
// ---------------------------------------------------------------------------
__global__ __launch_bounds__(256, 2) void gemm_kernel(
    const char* __restrict__ A8,    // SDIM x 3840 (i8)
    const char* __restrict__ W8,    // ODIM x 3840 (i8)
    const char* __restrict__ Afp,   // SDIM x 512 bytes (bf16)
    const char* __restrict__ Wfp,   // ODIM x 512 bytes (bf16)
    const float* __restrict__ qs,
    const float* __restrict__ wsc,
    const float* __restrict__ bias,
    float* __restrict__ out)        // SDIM x ODIM f32
{
  __shared__ char lds[2][2][128][128];   // 64 KiB: 2 dbuf x (A,B) x 128 rows x 128 B
  const int tid  = threadIdx.x;
  const int lane = tid & 63;
  const int wid  = tid >> 6;
  const int wr   = wid >> 1, wc = wid & 1;

  const int bid = blockIdx.x;
  const int swz = (bid & 7) * 64 + (bid >> 3);   // 512 % 8 == 0 -> bijective
  const int bm  = swz & 15;
  const int bn  = swz >> 4;
  const int srow0 = bm * 128;
  const int ocol0 = bn * 128;

  // Swizzled read offsets within a [128 rows][8 chunks of 16B] tile.
  // Logical chunk c = kk*4 + (lane>>4); physical chunk = c ^ (row & 7).
  int aoff[2][4], boff[2][4];
  #pragma unroll
  for (int kk = 0; kk < 2; ++kk) {
    #pragma unroll
    for (int i = 0; i < 4; ++i) {
      const int rowA = wr * 64 + i * 16 + (lane & 15);
      const int rowB = wc * 64 + i * 16 + (lane & 15);
      const int c    = kk * 4 + (lane >> 4);
      aoff[kk][i] = rowA * 128 + ((c ^ (rowA & 7)) * 16);
      boff[kk][i] = rowB * 128 + ((c ^ (rowB & 7)) * 16);
    }
  }

  // Staging: lane l writes LDS at groupbase + l*16 (row l>>3, phys chunk l&7);
  // fetch global logical chunk (l&7)^(row&7) so the read-side XOR un-swizzles.
  const int rloc0 = wid * 32 + (lane >> 3);      // + q*8
  const int clA   = (lane & 7);                  // physical chunk this lane fills

  auto stage8 = [&](int ktB, int buf) {
    #pragma unroll
    for (int q = 0; q < 4; ++q) {
      const int rl = rloc0 + q * 8;
      const int cl = clA ^ (rl & 7);
      gload16(A8 + (size_t)(srow0 + rl) * INTD + ktB + cl * 16,
              &lds[buf][0][wid * 32 + q * 8][0]);
      gload16(W8 + (size_t)(ocol0 + rl) * INTD + ktB + cl * 16,
              &lds[buf][1][wid * 32 + q * 8][0]);
    }
  };
  auto stagefp = [&](int ktB, int buf) {
    #pragma unroll
    for (int q = 0; q < 4; ++q) {
      const int rl = rloc0 + q * 8;
      const int cl = clA ^ (rl & 7);
      gload16(Afp + (size_t)(srow0 + rl) * 512 + ktB + cl * 16,
              &lds[buf][0][wid * 32 + q * 8][0]);
      gload16(Wfp + (size_t)(ocol0 + rl) * 512 + ktB + cl * 16,
              &lds[buf][1][wid * 32 + q * 8][0]);
    }
  };

  i32x4 iacc[4][4];
  #pragma unroll
  for (int i = 0; i < 4; ++i)
    #pragma unroll
    for (int j = 0; j < 4; ++j)
      iacc[i][j] = i32x4{0, 0, 0, 0};

  stage8(0, 0);
  int cur = 0;
  constexpr int NT8 = INTD / 128;   // 30
  for (int t = 0; t < NT8; ++t) {
    __syncthreads();
    if (t + 1 < NT8) stage8((t + 1) * 128, cur ^ 1);
    else             stagefp(0, cur ^ 1);
    const char* Al = &lds[cur][0][0][0];
    const char* Bl = &lds[cur][1][0][0];
    #pragma unroll
    for (int kk = 0; kk < 2; ++kk) {
      i32x4 af[4], bv[4];
      #pragma unroll
      for (int i = 0; i < 4; ++i) af[i] = *(const i32x4*)(Al + aoff[kk][i]);
      #pragma unroll
      for (int j = 0; j < 4; ++j) bv[j] = *(const i32x4*)(Bl + boff[kk][j]);
      #pragma unroll
      for (int i = 0; i < 4; ++i)
        #pragma unroll
        for (int j = 0; j < 4; ++j)
          iacc[i][j] = __builtin_amdgcn_mfma_i32_16x16x64_i8(
              af[i], bv[j], iacc[i][j], 0, 0, 0);
    }
    cur ^= 1;
  }

  // Convert: facc = iacc * wsc[o] * qs[s]  (overlaps with fp tile-0 load in flight)
  const int r4 = (lane >> 4) * 4;
  const int cn = lane & 15;
  float wo[4], qv[4][4];
  #pragma unroll
  for (int j = 0; j < 4; ++j) wo[j] = wsc[ocol0 + wc * 64 + j * 16 + cn];
  #pragma unroll
  for (int i = 0; i < 4; ++i)
    #pragma unroll
    for (int r = 0; r < 4; ++r)
      qv[i][r] = qs[srow0 + wr * 64 + i * 16 + r4 + r];

  f32x4 facc[4][4];
  #pragma unroll
  for (int i = 0; i < 4; ++i)
    #pragma unroll
    for (int j = 0; j < 4; ++j)
      #pragma unroll
      for (int r = 0; r < 4; ++r)
        facc[i][j][r] = (float)iacc[i][j][r] * wo[j] * qv[i][r];

  constexpr int NTF = (FPD * 2) / 128;   // 4 steps of 128 B (64 bf16)
  for (int t = 0; t < NTF; ++t) {
    __syncthreads();
    if (t + 1 < NTF) stagefp((t + 1) * 128, cur ^ 1);
    const char* Al = &lds[cur][0][0][0];
    const char* Bl = &lds[cur][1][0][0];
    #pragma unroll
    for (int kk = 0; kk < 2; ++kk) {
      bf16x8 af[4], bv[4];
      #pragma unroll
      for (int i = 0; i < 4; ++i) af[i] = *(const bf16x8*)(Al + aoff[kk][i]);
      #pragma unroll
      for (int j = 0; j < 4; ++j) bv[j] = *(const bf16x8*)(Bl + boff[kk][j]);
      #pragma unroll
      for (int i = 0; i < 4; ++i)
        #pragma unroll
        for (int j = 0; j < 4; ++j)
          facc[i][j] = __builtin_amdgcn_mfma_f32_16x16x32_bf16(
              af[i], bv[j], facc[i][j], 0, 0, 0);
    }
    cur ^= 1;
  }

  #pragma unroll
  for (int j = 0; j < 4; ++j) {
    const int o  = ocol0 + wc * 64 + j * 16 + cn;
    const float bo = bias[o];
    #pragma unroll
    for (int i = 0; i < 4; ++i) {
      const int sbase = srow0 + wr * 64 + i * 16 + r4;
      #pragma unroll
      for (int r = 0; r < 4; ++r)
        out[(size_t)(sbase + r) * ODIM + o] = facc[i][j][r] + bo;
    }
  }
}

// ---------------------------------------------------------------------------
extern "C" void kernel_launch(void* const* d_in, const int* in_sizes, int n_in,
                              void* d_out, int out_size, void* d_ws, size_t ws_size,
                              hipStream_t stream) {
  const float* x    = (const float*)d_in[0];
  const float* iw   = (const float*)d_in[1];
  const float* fw   = (const float*)d_in[2];
  const float* wsc  = (const float*)d_in[3];
  const float* bias = (const float*)d_in[4];
  const int* int_idx = (const int*)d_in[5];
  const int* fp_idx  = (const int*)d_in[6];
  float* out = (float*)d_out;

  char* ws = (char*)d_ws;
  char* A8  = ws;                                   // 2048*3840    = 7.86 MB
  char* W8  = A8 + (size_t)SDIM * INTD;             // 4096*3840    = 15.7 MB
  char* Afp = W8 + (size_t)ODIM * INTD;             // 2048*256*2   = 1.0 MB
  char* Wfp = Afp + (size_t)SDIM * FPD * 2;         // 4096*256*2   = 2.1 MB
  float* qs = (float*)(Wfp + (size_t)ODIM * FPD * 2);

  prep_x_kernel<<<SDIM, 256, 0, stream>>>(x, int_idx, fp_idx,
                                          (unsigned*)A8, (unsigned short*)Afp, qs);
  prep_w_kernel<<<ODIM, 256, 0, stream>>>(iw, fw, (unsigned*)W8, (unsigned short*)Wfp);
  gemm_kernel<<<512, 256, 0, stream>>>(A8, W8, Afp, Wfp, qs, wsc, bias, out);
}

// Round 5
// 177.499 us; speedup vs baseline: 1.1704x; 1.0345x over previous
//
#include <hip/hip_runtime.h>
#include <hip/hip_bf16.h>
#include <stdint.h>

typedef __attribute__((ext_vector_type(4))) float f32x4;
typedef __attribute__((ext_vector_type(8))) short bf16x8;
typedef __attribute__((ext_vector_type(4))) int i32x4;

constexpr int SDIM = 2048;
constexpr int ODIM = 4096;
constexpr int INTD = 3840;
constexpr int FPD  = 256;

// RNE float->bf16
__device__ __forceinline__ unsigned short f2bf(float f) {
  union { float f; unsigned u; } a; a.f = f;
  unsigned r = a.u + 0x7fffu + ((a.u >> 16) & 1u);
  return (unsigned short)(r >> 16);
}

__device__ __forceinline__ void gload16(const void* g, void* l) {
  __builtin_amdgcn_global_load_lds(
      (const __attribute__((address_space(1))) void*)g,
      (__attribute__((address_space(3))) void*)l, 16, 0, 0);
}

// ---------------------------------------------------------------------------
// Fused prep: blocks [0,2048) process x rows; blocks [2048,6144) process
// weight rows.  Both paths are streaming / BW-bound.
// ---------------------------------------------------------------------------
__global__ __launch_bounds__(256) void prep_kernel(
    const float* __restrict__ x,
    const float* __restrict__ iw,
    const float* __restrict__ fw,
    const int* __restrict__ int_idx,
    const int* __restrict__ fp_idx,
    unsigned* __restrict__ A8,          // [SDIM][960] packed i8x4
    unsigned short* __restrict__ Afp,   // [SDIM][FPD] bf16
    unsigned* __restrict__ W8,          // [ODIM][960] packed i8x4
    unsigned short* __restrict__ Wfp,   // [ODIM][FPD] bf16
    float* __restrict__ qs)
{
  const int t = threadIdx.x;
  if (blockIdx.x >= SDIM) {
    // ---- weight path: one output row per block ----
    const int o = blockIdx.x - SDIM;
    const float* iwr = iw + (size_t)o * INTD;
    unsigned* Wr = W8 + (size_t)o * 960;
    #pragma unroll
    for (int i = 0; i < 4; ++i) {
      const int g = t + (i << 8);
      if (g < 960) {
        float4 v = ((const float4*)iwr)[g];
        int q0 = __float2int_rn(v.x), q1 = __float2int_rn(v.y);
        int q2 = __float2int_rn(v.z), q3 = __float2int_rn(v.w);
        Wr[g] = (unsigned)(q0 & 255) | ((unsigned)(q1 & 255) << 8) |
                ((unsigned)(q2 & 255) << 16) | ((unsigned)(q3 & 255) << 24);
      }
    }
    Wfp[(size_t)o * FPD + t] = f2bf(fw[(size_t)o * FPD + t]);
    return;
  }

  // ---- activation path: one sequence row per block ----
  __shared__ float row[4096];
  __shared__ float red[4];
  const int s = blockIdx.x;
  const float* xr = x + (size_t)s * 4096;
  #pragma unroll
  for (int i = 0; i < 4; ++i)
    ((float4*)row)[t + 256 * i] = ((const float4*)xr)[t + 256 * i];
  __syncthreads();

  float vals[16];
  float m = 0.f;
  #pragma unroll
  for (int i = 0; i < 4; ++i) {
    const int g = t + (i << 8);
    if (g < 960) {
      int4 idx = ((const int4*)int_idx)[g];
      float v0 = row[idx.x], v1 = row[idx.y], v2 = row[idx.z], v3 = row[idx.w];
      vals[i*4+0] = v0; vals[i*4+1] = v1; vals[i*4+2] = v2; vals[i*4+3] = v3;
      m = fmaxf(m, fmaxf(fmaxf(fabsf(v0), fabsf(v1)), fmaxf(fabsf(v2), fabsf(v3))));
    }
  }
  #pragma unroll
  for (int off = 32; off; off >>= 1)
    m = fmaxf(m, __shfl_xor(m, off));
  if ((t & 63) == 0) red[t >> 6] = m;
  __syncthreads();
  const float mx = fmaxf(fmaxf(red[0], red[1]), fmaxf(red[2], red[3]));
  if (t == 0) qs[s] = mx / 127.0f;        // exactly as reference: max/QMAX
  const float rcp = 127.0f / mx;          // one divide; 15 FMAs below

  unsigned* Ar = A8 + (size_t)s * 960;
  #pragma unroll
  for (int i = 0; i < 4; ++i) {
    const int g = t + (i << 8);
    if (g < 960) {
      unsigned pk = 0;
      #pragma unroll
      for (int e = 0; e < 4; ++e) {
        float q = rintf(vals[i*4+e] * rcp);   // round-half-even == jnp.round
        q = fminf(fmaxf(q, -128.f), 127.f);
        pk |= ((unsigned)((int)q & 255)) << (e * 8);
      }
      Ar[g] = pk;
    }
  }
  Afp[(size_t)s * FPD + t] = f2bf(row[fp_idx[t]]);   // raw fp_x (unscaled)
}

// ---------------------------------------------------------------------------
// GEMM (unchanged from round 3): fused i8 (K=3840) + bf16 (K=256)
// out[s,o] = (i8dot)*wsc[o]*qs[s] + (fp dot) + bias[o]
// ---------------------------------------------------------------------------
__global__ __launch_bounds__(256, 2) void gemm_kernel(
    const char* __restrict__ A8,    // SDIM x 3840 (i8)
    const char* __restrict__ W8,    // ODIM x 3840 (i8)
    const char* __restrict__ Afp,   // SDIM x 512 bytes (bf16)
    const char* __restrict__ Wfp,   // ODIM x 512 bytes (bf16)
    const float* __restrict__ qs,
    const float* __restrict__ wsc,
    const float* __restrict__ bias,
    float* __restrict__ out)        // SDIM x ODIM f32
{
  __shared__ char lds[2][2][128][128];   // 64 KiB
  const int tid  = threadIdx.x;
  const int lane = tid & 63;
  const int wid  = tid >> 6;
  const int wr   = wid >> 1, wc = wid & 1;

  const int bid = blockIdx.x;
  const int swz = (bid & 7) * 64 + (bid >> 3);   // 512 % 8 == 0 -> bijective
  const int bm  = swz & 15;
  const int bn  = swz >> 4;
  const int srow0 = bm * 128;
  const int ocol0 = bn * 128;

  int aoff[2][4], boff[2][4];
  #pragma unroll
  for (int kk = 0; kk < 2; ++kk) {
    #pragma unroll
    for (int i = 0; i < 4; ++i) {
      const int rowA = wr * 64 + i * 16 + (lane & 15);
      const int rowB = wc * 64 + i * 16 + (lane & 15);
      const int c    = kk * 4 + (lane >> 4);
      aoff[kk][i] = rowA * 128 + ((c ^ (rowA & 7)) * 16);
      boff[kk][i] = rowB * 128 + ((c ^ (rowB & 7)) * 16);
    }
  }

  const int rloc0 = wid * 32 + (lane >> 3);
  const int clA   = (lane & 7);

  auto stage8 = [&](int ktB, int buf) {
    #pragma unroll
    for (int q = 0; q < 4; ++q) {
      const int rl = rloc0 + q * 8;
      const int cl = clA ^ (rl & 7);
      gload16(A8 + (size_t)(srow0 + rl) * INTD + ktB + cl * 16,
              &lds[buf][0][wid * 32 + q * 8][0]);
      gload16(W8 + (size_t)(ocol0 + rl) * INTD + ktB + cl * 16,
              &lds[buf][1][wid * 32 + q * 8][0]);
    }
  };
  auto stagefp = [&](int ktB, int buf) {
    #pragma unroll
    for (int q = 0; q < 4; ++q) {
      const int rl = rloc0 + q * 8;
      const int cl = clA ^ (rl & 7);
      gload16(Afp + (size_t)(srow0 + rl) * 512 + ktB + cl * 16,
              &lds[buf][0][wid * 32 + q * 8][0]);
      gload16(Wfp + (size_t)(ocol0 + rl) * 512 + ktB + cl * 16,
              &lds[buf][1][wid * 32 + q * 8][0]);
    }
  };

  i32x4 iacc[4][4];
  #pragma unroll
  for (int i = 0; i < 4; ++i)
    #pragma unroll
    for (int j = 0; j < 4; ++j)
      iacc[i][j] = i32x4{0, 0, 0, 0};

  stage8(0, 0);
  int cur = 0;
  constexpr int NT8 = INTD / 128;   // 30
  for (int t = 0; t < NT8; ++t) {
    __syncthreads();
    if (t + 1 < NT8) stage8((t + 1) * 128, cur ^ 1);
    else             stagefp(0, cur ^ 1);
    const char* Al = &lds[cur][0][0][0];
    const char* Bl = &lds[cur][1][0][0];
    #pragma unroll
    for (int kk = 0; kk < 2; ++kk) {
      i32x4 af[4], bv[4];
      #pragma unroll
      for (int i = 0; i < 4; ++i) af[i] = *(const i32x4*)(Al + aoff[kk][i]);
      #pragma unroll
      for (int j = 0; j < 4; ++j) bv[j] = *(const i32x4*)(Bl + boff[kk][j]);
      #pragma unroll
      for (int i = 0; i < 4; ++i)
        #pragma unroll
        for (int j = 0; j < 4; ++j)
          iacc[i][j] = __builtin_amdgcn_mfma_i32_16x16x64_i8(
              af[i], bv[j], iacc[i][j], 0, 0, 0);
    }
    cur ^= 1;
  }

  const int r4 = (lane >> 4) * 4;
  const int cn = lane & 15;
  float wo[4], qv[4][4];
  #pragma unroll
  for (int j = 0; j < 4; ++j) wo[j] = wsc[ocol0 + wc * 64 + j * 16 + cn];
  #pragma unroll
  for (int i = 0; i < 4; ++i)
    #pragma unroll
    for (int r = 0; r < 4; ++r)
      qv[i][r] = qs[srow0 + wr * 64 + i * 16 + r4 + r];

  f32x4 facc[4][4];
  #pragma unroll
  for (int i = 0; i < 4; ++i)
    #pragma unroll
    for (int j = 0; j < 4; ++j)
      #pragma unroll
      for (int r = 0; r < 4; ++r)
        facc[i][j][r] = (float)iacc[i][j][r] * wo[j] * qv[i][r];

  constexpr int NTF = (FPD * 2) / 128;   // 4
  for (int t = 0; t < NTF; ++t) {
    __syncthreads();
    if (t + 1 < NTF) stagefp((t + 1) * 128, cur ^ 1);
    const char* Al = &lds[cur][0][0][0];
    const char* Bl = &lds[cur][1][0][0];
    #pragma unroll
    for (int kk = 0; kk < 2; ++kk) {
      bf16x8 af[4], bv[4];
      #pragma unroll
      for (int i = 0; i < 4; ++i) af[i] = *(const bf16x8*)(Al + aoff[kk][i]);
      #pragma unroll
      for (int j = 0; j < 4; ++j) bv[j] = *(const bf16x8*)(Bl + boff[kk][j]);
      #pragma unroll
      for (int i = 0; i < 4; ++i)
        #pragma unroll
        for (int j = 0; j < 4; ++j)
          facc[i][j] = __builtin_amdgcn_mfma_f32_16x16x32_bf16(
              af[i], bv[j], facc[i][j], 0, 0, 0);
    }
    cur ^= 1;
  }

  #pragma unroll
  for (int j = 0; j < 4; ++j) {
    const int o  = ocol0 + wc * 64 + j * 16 + cn;
    const float bo = bias[o];
    #pragma unroll
    for (int i = 0; i < 4; ++i) {
      const int sbase = srow0 + wr * 64 + i * 16 + r4;
      #pragma unroll
      for (int r = 0; r < 4; ++r)
        out[(size_t)(sbase + r) * ODIM + o] = facc[i][j][r] + bo;
    }
  }
}

// ---------------------------------------------------------------------------
extern "C" void kernel_launch(void* const* d_in, const int* in_sizes, int n_in,
                              void* d_out, int out_size, void* d_ws, size_t ws_size,
                              hipStream_t stream) {
  const float* x    = (const float*)d_in[0];
  const float* iw   = (const float*)d_in[1];
  const float* fw   = (const float*)d_in[2];
  const float* wsc  = (const float*)d_in[3];
  const float* bias = (const float*)d_in[4];
  const int* int_idx = (const int*)d_in[5];
  const int* fp_idx  = (const int*)d_in[6];
  float* out = (float*)d_out;

  char* ws = (char*)d_ws;
  char* A8  = ws;                                   // 2048*3840    = 7.86 MB
  char* W8  = A8 + (size_t)SDIM * INTD;             // 4096*3840    = 15.7 MB
  char* Afp = W8 + (size_t)ODIM * INTD;             // 2048*256*2   = 1.0 MB
  char* Wfp = Afp + (size_t)SDIM * FPD * 2;         // 4096*256*2   = 2.1 MB
  float* qs = (float*)(Wfp + (size_t)ODIM * FPD * 2);

  prep_kernel<<<SDIM + ODIM, 256, 0, stream>>>(x, iw, fw, int_idx, fp_idx,
                                               (unsigned*)A8, (unsigned short*)Afp,
                                               (unsigned*)W8, (unsigned short*)Wfp, qs);
  gemm_kernel<<<512, 256, 0, stream>>>(A8, W8, Afp, Wfp, qs, wsc, bias, out);
}